// Round 8
// baseline (167.184 us; speedup 1.0000x reference)
//
#include <hip/hip_runtime.h>
#include <cstddef>

// B=2,H=16 -> BH=32
#define BH    32
#define NSEQ  4096
#define MFEAT 256
#define CHUNK 128
#define NCH   32
#define SROW  65          // 64 d-rows + 1 z-row
#define SPITCH (SROW*256) // 16640 f16 per (bh,chunk) state

#define SCALE 0.35355339059327373f  // 64^-0.25

typedef unsigned int uint_t;
typedef _Float16 half_t;
typedef __attribute__((ext_vector_type(8))) _Float16 half8;
typedef __attribute__((ext_vector_type(4))) float f32x4;

__device__ __forceinline__ f32x4 mfma16(half8 a, half8 b, f32x4 c) {
  return __builtin_amdgcn_mfma_f32_16x16x32_f16(a, b, c, 0, 0, 0);
}
__device__ __forceinline__ uint_t enc_f(float x) {
  uint_t u = __float_as_uint(x);
  return (u & 0x80000000u) ? ~u : (u | 0x80000000u);
}
__device__ __forceinline__ float dec_f(uint_t u) {
  u = (u & 0x80000000u) ? (u ^ 0x80000000u) : ~u;
  return __uint_as_float(u);
}
__device__ __forceinline__ half8 cvt_h8(float4 a, float4 b) {
  half8 h;
  h[0] = (half_t)a.x; h[1] = (half_t)a.y; h[2] = (half_t)a.z; h[3] = (half_t)a.w;
  h[4] = (half_t)b.x; h[5] = (half_t)b.y; h[6] = (half_t)b.z; h[7] = (half_t)b.w;
  return h;
}

__global__ void k_init(uint_t* kmax) { *kmax = enc_f(-__builtin_inff()); }

// ============================================================================
// k_maxes3: 64 rows of q AND k per block.
//   q: proj -> rowmax -> phiQ = exp(proj - rowmax)/16 + 1e-4, WRITTEN (64MB)
//   k: kh f16 copy (16MB), hnK (0.5|k_s|^2), blockmax -> atomicMax kmax
// ============================================================================
__global__ __launch_bounds__(256, 2) void k_maxes3(
    const float* __restrict__ q, const float* __restrict__ kx,
    const float* __restrict__ omega, uint_t* __restrict__ kmax,
    half_t* __restrict__ phiQ, half_t* __restrict__ kh,
    float* __restrict__ hnKg)
{
  __shared__ half_t Wl[256 * 72];   // omega f16; reused as phi staging
  __shared__ float nrm[64];
  __shared__ float red[4];

  const int tid = threadIdx.x;
  const int lane = tid & 63;
  const int w = tid >> 6;
  const int lc = lane & 15, rg = lane >> 4, koff = rg * 8;
  const size_t rowbase = (size_t)blockIdx.x * 64;

  // omega fp32 -> f16 LDS
  for (int l = tid; l < 4096; l += 256) {
    int m = l >> 4, d4 = (l & 15) * 4;
    float4 o = *(const float4*)(omega + m * 64 + d4);
    half_t* p = &Wl[m * 72 + d4];
    p[0] = (half_t)o.x; p[1] = (half_t)o.y; p[2] = (half_t)o.z; p[3] = (half_t)o.w;
  }
  // q,k a-frags direct to regs; write kh; k row norms via shfl
  half8 aq[2], akf[2];
  {
    const float* qp = q + (rowbase + w * 16 + lc) * 64 + koff;
    const float* kp = kx + (rowbase + w * 16 + lc) * 64 + koff;
    float pn = 0.f;
    #pragma unroll
    for (int ks = 0; ks < 2; ks++) {
      float4 a = *(const float4*)(qp + ks * 32);
      float4 b = *(const float4*)(qp + ks * 32 + 4);
      a.x *= SCALE; a.y *= SCALE; a.z *= SCALE; a.w *= SCALE;
      b.x *= SCALE; b.y *= SCALE; b.z *= SCALE; b.w *= SCALE;
      aq[ks] = cvt_h8(a, b);
      float4 c = *(const float4*)(kp + ks * 32);
      float4 d = *(const float4*)(kp + ks * 32 + 4);
      c.x *= SCALE; c.y *= SCALE; c.z *= SCALE; c.w *= SCALE;
      d.x *= SCALE; d.y *= SCALE; d.z *= SCALE; d.w *= SCALE;
      pn += c.x * c.x + c.y * c.y + c.z * c.z + c.w * c.w
          + d.x * d.x + d.y * d.y + d.z * d.z + d.w * d.w;
      akf[ks] = cvt_h8(c, d);
    }
    #pragma unroll
    for (int ks = 0; ks < 2; ks++)
      *(half8*)(kh + (rowbase + w * 16 + lc) * 64 + ks * 32 + koff) = akf[ks];
    pn += __shfl_xor(pn, 16, 64);
    pn += __shfl_xor(pn, 32, 64);
    if (rg == 0) {
      nrm[w * 16 + lc] = 0.5f * pn;
      hnKg[rowbase + w * 16 + lc] = 0.5f * pn;
    }
  }
  __syncthreads();

  // ---- k proj -> block max ----
  {
    f32x4 acc[16];
    #pragma unroll
    for (int ct = 0; ct < 16; ct++) acc[ct] = (f32x4){0.f, 0.f, 0.f, 0.f};
    #pragma unroll
    for (int ks = 0; ks < 2; ks++)
      #pragma unroll
      for (int ct = 0; ct < 16; ct++) {
        half8 b = *(const half8*)&Wl[(ct * 16 + lc) * 72 + ks * 32 + koff];
        acc[ct] = mfma16(akf[ks], b, acc[ct]);
      }
    float hn[4];
    #pragma unroll
    for (int r = 0; r < 4; r++) hn[r] = nrm[w * 16 + rg * 4 + r];
    float bm = -3.4e38f;
    #pragma unroll
    for (int ct = 0; ct < 16; ct++)
      #pragma unroll
      for (int r = 0; r < 4; r++) bm = fmaxf(bm, acc[ct][r] - hn[r]);
    #pragma unroll
    for (int off = 1; off < 64; off <<= 1) bm = fmaxf(bm, __shfl_xor(bm, off, 64));
    if (lane == 0) red[w] = bm;
  }

  // ---- q proj -> rowmax -> phi (in-place in acc) ----
  f32x4 acc[16];
  #pragma unroll
  for (int ct = 0; ct < 16; ct++) acc[ct] = (f32x4){0.f, 0.f, 0.f, 0.f};
  #pragma unroll
  for (int ks = 0; ks < 2; ks++)
    #pragma unroll
    for (int ct = 0; ct < 16; ct++) {
      half8 b = *(const half8*)&Wl[(ct * 16 + lc) * 72 + ks * 32 + koff];
      acc[ct] = mfma16(aq[ks], b, acc[ct]);
    }
  float rowm[4];
  #pragma unroll
  for (int r = 0; r < 4; r++) {
    float m0 = -3.4e38f;
    #pragma unroll
    for (int ct = 0; ct < 16; ct++) m0 = fmaxf(m0, acc[ct][r]);
    m0 = fmaxf(m0, __shfl_xor(m0, 1, 64));
    m0 = fmaxf(m0, __shfl_xor(m0, 2, 64));
    m0 = fmaxf(m0, __shfl_xor(m0, 4, 64));
    m0 = fmaxf(m0, __shfl_xor(m0, 8, 64));
    rowm[r] = m0;
  }
  #pragma unroll
  for (int ct = 0; ct < 16; ct++)
    #pragma unroll
    for (int r = 0; r < 4; r++)
      acc[ct][r] = __expf(acc[ct][r] - rowm[r]) * 0.0625f + 1e-4f;

  __syncthreads();   // red visible; all Wl reads done
  if (tid == 0)
    atomicMax(kmax, enc_f(fmaxf(fmaxf(red[0], red[1]), fmaxf(red[2], red[3]))));

  // stage phi -> Wl reuse [64][264], then coalesced write
  half_t* st = Wl;
  #pragma unroll
  for (int ct = 0; ct < 16; ct++)
    #pragma unroll
    for (int r = 0; r < 4; r++)
      st[(w * 16 + rg * 4 + r) * 264 + ct * 16 + lc] = (half_t)acc[ct][r];
  __syncthreads();
  #pragma unroll
  for (int e = 0; e < 8; e++) {
    int l = tid + e * 256;
    int row = l >> 5, c = (l & 31) * 8;
    *(half8*)(phiQ + (rowbase + row) * 256 + c) = *(const half8*)&st[row * 264 + c];
  }
}

// ============================================================================
// k_state3: fused phi_k projection + chunk partial state + phiK emission.
// ============================================================================
__global__ __launch_bounds__(256, 2) void k_state3(
    const half_t* __restrict__ kh, const float* __restrict__ v,
    const float* __restrict__ omega, const float* __restrict__ hnKg,
    const uint_t* __restrict__ kmax, half_t* __restrict__ spA,
    half_t* __restrict__ phiKg)
{
  __shared__ half_t WP[256 * 72];   // omega; aliased by pkT[128][144] & PhS[128][136]
  __shared__ half_t vt[80 * 136];   // [d'][j]; row64=ones

  const int tid = threadIdx.x;
  const int lane = tid & 63;
  const int w = tid >> 6;
  const int lc = lane & 15, rg = lane >> 4, koff = rg * 8;
  const int wr = w * 32;
  const int blk = blockIdx.x;
  const size_t nbase = (size_t)(blk >> 5) * NSEQ + (size_t)(blk & 31) * CHUNK;
  const float gmaxv = dec_f(*kmax);

  for (int l = tid; l < 4096; l += 256) {
    int m = l >> 4, d4 = (l & 15) * 4;
    float4 o = *(const float4*)(omega + m * 64 + d4);
    half_t* p = &WP[m * 72 + d4];
    p[0] = (half_t)o.x; p[1] = (half_t)o.y; p[2] = (half_t)o.z; p[3] = (half_t)o.w;
  }
  for (int l = tid; l < 2048; l += 256) {
    int j = l >> 4, dq = (l & 15) * 4;
    float4 vv = *(const float4*)(v + (nbase + j) * 64 + dq);
    vt[(dq + 0) * 136 + j] = (half_t)vv.x;
    vt[(dq + 1) * 136 + j] = (half_t)vv.y;
    vt[(dq + 2) * 136 + j] = (half_t)vv.z;
    vt[(dq + 3) * 136 + j] = (half_t)vv.w;
  }
  if (tid < 128) vt[64 * 136 + tid] = (half_t)1.0f;

  half8 ak[2][2];
  float hnr[2][4];
  #pragma unroll
  for (int rt = 0; rt < 2; rt++) {
    const half_t* kp = kh + (nbase + wr + rt * 16 + lc) * 64 + koff;
    ak[rt][0] = *(const half8*)(kp);
    ak[rt][1] = *(const half8*)(kp + 32);
    #pragma unroll
    for (int r = 0; r < 4; r++)
      hnr[rt][r] = hnKg[nbase + wr + rt * 16 + rg * 4 + r];
  }
  __syncthreads();

  f32x4 accP[2][16];
  #pragma unroll
  for (int rt = 0; rt < 2; rt++)
    #pragma unroll
    for (int ct = 0; ct < 16; ct++) accP[rt][ct] = (f32x4){0.f, 0.f, 0.f, 0.f};
  #pragma unroll
  for (int ks = 0; ks < 2; ks++)
    #pragma unroll
    for (int ct = 0; ct < 16; ct++) {
      half8 b = *(const half8*)&WP[(ct * 16 + lc) * 72 + ks * 32 + koff];
      accP[0][ct] = mfma16(ak[0][ks], b, accP[0][ct]);
      accP[1][ct] = mfma16(ak[1][ks], b, accP[1][ct]);
    }
  #pragma unroll
  for (int rt = 0; rt < 2; rt++)
    #pragma unroll
    for (int ct = 0; ct < 16; ct++)
      #pragma unroll
      for (int r = 0; r < 4; r++)
        accP[rt][ct][r] = __expf(accP[rt][ct][r] - hnr[rt][r] - gmaxv) * 0.0625f + 1e-4f;

  half_t* pkT = WP;  // [128][144]
  #pragma unroll
  for (int h = 0; h < 2; h++) {
    __syncthreads();
    #pragma unroll
    for (int rt = 0; rt < 2; rt++)
      #pragma unroll
      for (int c8 = 0; c8 < 8; c8++) {
        int ct = h * 8 + c8;
        #pragma unroll
        for (int r = 0; r < 4; r++)
          pkT[(c8 * 16 + lc) * 144 + wr + rt * 16 + rg * 4 + r] = (half_t)accP[rt][ct][r];
      }
    __syncthreads();
    f32x4 acc2[5][2];
    #pragma unroll
    for (int rt = 0; rt < 5; rt++) {
      acc2[rt][0] = (f32x4){0.f, 0.f, 0.f, 0.f};
      acc2[rt][1] = (f32x4){0.f, 0.f, 0.f, 0.f};
    }
    #pragma unroll
    for (int ks = 0; ks < 4; ks++) {
      half8 b0 = *(const half8*)&pkT[((2 * w + 0) * 16 + lc) * 144 + ks * 32 + koff];
      half8 b1 = *(const half8*)&pkT[((2 * w + 1) * 16 + lc) * 144 + ks * 32 + koff];
      #pragma unroll
      for (int rt = 0; rt < 5; rt++) {
        half8 a = *(const half8*)&vt[(rt * 16 + lc) * 136 + ks * 32 + koff];
        acc2[rt][0] = mfma16(a, b0, acc2[rt][0]);
        acc2[rt][1] = mfma16(a, b1, acc2[rt][1]);
      }
    }
    #pragma unroll
    for (int rt = 0; rt < 5; rt++)
      #pragma unroll
      for (int c2 = 0; c2 < 2; c2++)
        #pragma unroll
        for (int r = 0; r < 4; r++) {
          int row = rt * 16 + rg * 4 + r;
          if (row < SROW)
            spA[(size_t)blk * SPITCH + row * 256 + h * 128 + (2 * w + c2) * 16 + lc] =
                (half_t)acc2[rt][c2][r];
        }
  }

  // ---- phiK emission: re-stage accP into [j][m] halves, coalesced write ----
  half_t* PhS = WP;  // [128][136]
  #pragma unroll
  for (int hh = 0; hh < 2; hh++) {
    __syncthreads();   // pkT reads (and prev PhS reads) complete
    #pragma unroll
    for (int rt = 0; rt < 2; rt++)
      #pragma unroll
      for (int c8 = 0; c8 < 8; c8++)
        #pragma unroll
        for (int r = 0; r < 4; r++)
          PhS[(wr + rt * 16 + rg * 4 + r) * 136 + c8 * 16 + lc] =
              (half_t)accP[rt][hh * 8 + c8][r];
    __syncthreads();
    #pragma unroll
    for (int e = 0; e < 8; e++) {
      int l = tid + e * 256;
      int j = l >> 4, c8b = (l & 15) * 8;
      *(half8*)(phiKg + (nbase + j) * 256 + hh * 128 + c8b) =
          *(const half8*)&PhS[j * 136 + c8b];
    }
  }
}

// ============================================================================
// k_prefix: exclusive prefix over 32 chunks, f16->f16, fp32 accum (unchanged).
// ============================================================================
__global__ __launch_bounds__(256) void k_prefix(
    const uint_t* __restrict__ spA, uint_t* __restrict__ spB)
{
  int r = blockIdx.x * 256 + threadIdx.x;
  if (r >= SPITCH / 2) return;
  int bh = blockIdx.y;
  const uint_t* src = spA + (size_t)bh * NCH * (SPITCH / 2) + r;
  uint_t* dst = spB + (size_t)bh * NCH * (SPITCH / 2) + r;
  float r0 = 0.f, r1 = 0.f;
  for (int c = 0; c < NCH; c++) {
    union { uint_t u; half_t h[2]; } cv, ov;
    cv.u = src[(size_t)c * (SPITCH / 2)];
    ov.h[0] = (half_t)r0; ov.h[1] = (half_t)r1;
    dst[(size_t)c * (SPITCH / 2)] = ov.u;
    r0 += (float)cv.h[0];
    r1 += (float)cv.h[1];
  }
}

// ============================================================================
// k_attn8: pure consumer, TRANSPOSED formulation, 512 threads / 8 waves.
//   accA[it] = D[j][i] = sum_m phiK[j][m] * phiQ[i][m]   (wave owns j-tile w)
//   accO[cs] = D2[d'][i] = sum_m SST[d'][m] * phiQ[i][m]
//            += sum_j VT[d'][j] * ASmask[i][j]           (wave owns i-tile w)
//   den = row 64 of accO (z-row of SST + ones-row of VT); out = cols/den.
// phiK: direct global->reg frags (wave-private rows, no LDS, no transpose).
// LDS 36864 B: PQ[128][64]swz @0 | SST[80][64]swz @8192 (phase1)
//              AS[128][64]swz @0 | VT[80][128]swz @8192  (phase2, j-halves)
//              OS f32[128][68] @0                        (epilogue)
// ============================================================================
__global__ __launch_bounds__(512) void k_attn8(
    const half_t* __restrict__ phiQ, const half_t* __restrict__ phiK,
    const float* __restrict__ v, const half_t* __restrict__ spB,
    float* __restrict__ out)
{
  __shared__ half_t sm[18432];
  half_t* PQ  = sm;            // [128][64] swz
  half_t* SST = sm + 8192;     // [80][64] swz (rows 0..64 valid)
  half_t* AS  = sm;            // phase2 alias
  half_t* VT  = sm + 8192;     // phase2 [80][128] swz

  const int tid = threadIdx.x;
  const int lane = tid & 63;
  const int w = tid >> 6;                 // 0..7
  const int lc = lane & 15, rg = lane >> 4, koff = rg * 8;
  const int blk = blockIdx.x;
  const size_t nbase = (size_t)(blk >> 5) * NSEQ + (size_t)(blk & 31) * CHUNK;
  const half_t* spb = spB + (size_t)blk * SPITCH;
  const int swz = (lc & 7) << 3;

  f32x4 accA[8], accO[5];
  #pragma unroll
  for (int it = 0; it < 8; it++) accA[it] = (f32x4){0.f, 0.f, 0.f, 0.f};
  #pragma unroll
  for (int cs = 0; cs < 5; cs++) accO[cs] = (f32x4){0.f, 0.f, 0.f, 0.f};

  // ---- phase 1: 4 m-tiles ----
  for (int mt = 0; mt < 4; mt++) {
    if (mt) __syncthreads();   // prev compute done before overwrite
    // stage PQ [128][64] (2 half8/thread)
    #pragma unroll
    for (int e = 0; e < 2; e++) {
      int l = tid + e * 512;
      int ro = l >> 3, c8 = (l & 7) * 8;
      *(half8*)&PQ[ro * 64 + (c8 ^ ((ro & 7) << 3))] =
          *(const half8*)(phiQ + (nbase + ro) * 256 + mt * 64 + c8);
    }
    // stage SST [65][64]
    { int ro = tid >> 3, c8 = (tid & 7) * 8;
      if (tid < 520)
        *(half8*)&SST[ro * 64 + (c8 ^ ((ro & 7) << 3))] =
            *(const half8*)(spb + ro * 256 + mt * 64 + c8); }
    if (tid < 8) { int l = tid + 512; int ro = l >> 3, c8 = (l & 7) * 8;
      *(half8*)&SST[ro * 64 + (c8 ^ ((ro & 7) << 3))] =
          *(const half8*)(spb + ro * 256 + mt * 64 + c8); }
    // phiK a-frags: wave-private rows j = w*16+lc, direct global
    half8 af0 = *(const half8*)(phiK + (nbase + w * 16 + lc) * 256 + mt * 64 + koff);
    half8 af1 = *(const half8*)(phiK + (nbase + w * 16 + lc) * 256 + mt * 64 + 32 + koff);
    __syncthreads();
    #pragma unroll
    for (int ks2 = 0; ks2 < 64; ks2 += 32) {
      half8 a = ks2 ? af1 : af0;
      int sA = (ks2 + koff) ^ swz;
      half8 bO = *(const half8*)&PQ[(w * 16 + lc) * 64 + sA];
      #pragma unroll
      for (int it = 0; it < 8; it++) {
        half8 b = *(const half8*)&PQ[(it * 16 + lc) * 64 + sA];
        accA[it] = mfma16(a, b, accA[it]);
      }
      #pragma unroll
      for (int cs = 0; cs < 5; cs++) {
        half8 as_ = *(const half8*)&SST[(cs * 16 + lc) * 64 + sA];
        accO[cs] = mfma16(as_, bO, accO[cs]);
      }
    }
  }
  __syncthreads();

  // ---- phase 2: VT stage + masked A @ v in two j-halves ----
  #pragma unroll
  for (int e = 0; e < 4; e++) {
    int l = tid + e * 512;
    int j = l >> 4, dq = (l & 15) * 4;
    float4 vv = *(const float4*)(v + (nbase + j) * 64 + dq);
    VT[(dq + 0) * 128 + (j ^ (((dq + 0) & 7) << 3))] = (half_t)vv.x;
    VT[(dq + 1) * 128 + (j ^ (((dq + 1) & 7) << 3))] = (half_t)vv.y;
    VT[(dq + 2) * 128 + (j ^ (((dq + 2) & 7) << 3))] = (half_t)vv.z;
    VT[(dq + 3) * 128 + (j ^ (((dq + 3) & 7) << 3))] = (half_t)vv.w;
  }
  if (tid < 128) VT[64 * 128 + tid] = (half_t)1.0f;   // (64&7)=0: no swz

  #pragma unroll
  for (int h = 0; h < 2; h++) {
    if ((w >> 2) == h) {   // waves owning j in this half write their masked A^T
      #pragma unroll
      for (int it = 0; it < 8; it++) {
        int i = it * 16 + lc;
        #pragma unroll
        for (int r = 0; r < 4; r++) {
          int j = w * 16 + rg * 4 + r;
          float val = (j <= i) ? accA[it][r] : 0.f;
          AS[i * 64 + ((j - h * 64) ^ ((i & 7) << 3))] = (half_t)val;
        }
      }
    }
    __syncthreads();
    #pragma unroll
    for (int ks2 = 0; ks2 < 64; ks2 += 32) {
      int sj = (ks2 + koff) ^ swz;
      half8 b = *(const half8*)&AS[(w * 16 + lc) * 64 + sj];
      #pragma unroll
      for (int cs = 0; cs < 5; cs++) {
        half8 a = *(const half8*)&VT[(cs * 16 + lc) * 128 + ((h * 64 + ks2 + koff) ^ swz)];
        accO[cs] = mfma16(a, b, accO[cs]);
      }
    }
    __syncthreads();
  }

  // ---- epilogue: den (row 64 -> accO[4][0] at rg==0), OS stage, store ----
  float den = __shfl(accO[4][0], lane & 15, 64) + 1e-6f;
  float inv = 1.0f / den;
  float* OS = (float*)sm;   // [128][68]
  #pragma unroll
  for (int cs = 0; cs < 4; cs++)
    #pragma unroll
    for (int r = 0; r < 4; r++)
      OS[(w * 16 + lc) * 68 + cs * 16 + rg * 4 + r] = accO[cs][r] * inv;
  __syncthreads();
  #pragma unroll
  for (int e = 0; e < 4; e++) {
    int l = tid + e * 512;
    int row = l >> 4, c4 = (l & 15) * 4;
    *(float4*)(out + (nbase + row) * 64 + c4) = *(const float4*)&OS[row * 68 + c4];
  }
}

// ============================================================================
// launcher
// ws layout (aliasing: spB overlays kh — kh's last read (k_state3) precedes
// spB's write (k_prefix) in stream order):
//   hnK  f32 @0          (512K)
//   kh   f16 @524288     (16M)   | spB f16 @524288 (34,078,720)
//   phiQ f16 @34603008   (64M)
//   phiK f16 @101711872  (64M)
//   spA  f16 @168820736  (34,078,720)
//   kmax u32 @202899456            -> ~202.9 MB total (same as R1, fits)
// ============================================================================
extern "C" void kernel_launch(void* const* d_in, const int* in_sizes, int n_in,
                              void* d_out, int out_size, void* d_ws, size_t ws_size,
                              hipStream_t stream) {
  const float* q = (const float*)d_in[0];
  const float* k = (const float*)d_in[1];
  const float* v = (const float*)d_in[2];
  const float* omega = (const float*)d_in[3];
  float* out = (float*)d_out;
  char* ws = (char*)d_ws;

  float*  hnKg = (float*)(ws + 0);
  half_t* kh   = (half_t*)(ws + 524288);
  half_t* spB  = (half_t*)(ws + 524288);
  half_t* phiQ = (half_t*)(ws + 34603008);
  half_t* phiK = (half_t*)(ws + 101711872);
  half_t* spA  = (half_t*)(ws + 168820736);
  uint_t* kmax = (uint_t*)(ws + 202899456);

  k_init<<<1, 1, 0, stream>>>(kmax);
  k_maxes3<<<2048, 256, 0, stream>>>(q, k, omega, kmax, phiQ, kh, hnKg);
  k_state3<<<1024, 256, 0, stream>>>(kh, v, omega, hnKg, kmax, spA, phiK);
  k_prefix<<<dim3(33, 32), 256, 0, stream>>>((const uint_t*)spA, (uint_t*)spB);
  k_attn8<<<1024, 512, 0, stream>>>(phiQ, phiK, v, spB, out);
}

// Round 9
// 154.617 us; speedup vs baseline: 1.0813x; 1.0813x over previous
//
#include <hip/hip_runtime.h>
#include <cstddef>

// B=2,H=16 -> BH=32
#define BH    32
#define NSEQ  4096
#define MFEAT 256
#define CHUNK 128
#define NCH   32
#define SROW  65          // 64 d-rows + 1 z-row
#define SPITCH (SROW*256) // 16640 f16 per (bh,chunk) state

#define SCALE 0.35355339059327373f  // 64^-0.25

typedef unsigned int uint_t;
typedef _Float16 half_t;
typedef __attribute__((ext_vector_type(8))) _Float16 half8;
typedef __attribute__((ext_vector_type(4))) float f32x4;

__device__ __forceinline__ f32x4 mfma16(half8 a, half8 b, f32x4 c) {
  return __builtin_amdgcn_mfma_f32_16x16x32_f16(a, b, c, 0, 0, 0);
}
__device__ __forceinline__ uint_t enc_f(float x) {
  uint_t u = __float_as_uint(x);
  return (u & 0x80000000u) ? ~u : (u | 0x80000000u);
}
__device__ __forceinline__ float dec_f(uint_t u) {
  u = (u & 0x80000000u) ? (u ^ 0x80000000u) : ~u;
  return __uint_as_float(u);
}
__device__ __forceinline__ half8 cvt_h8(float4 a, float4 b) {
  half8 h;
  h[0] = (half_t)a.x; h[1] = (half_t)a.y; h[2] = (half_t)a.z; h[3] = (half_t)a.w;
  h[4] = (half_t)b.x; h[5] = (half_t)b.y; h[6] = (half_t)b.z; h[7] = (half_t)b.w;
  return h;
}

__global__ void k_init(uint_t* kmax) { *kmax = enc_f(-__builtin_inff()); }

// ============================================================================
// k_maxes4: 64 rows of q AND k per block.
//   q: proj -> rowmax -> phiQ = exp(proj-rowmax)/16 + 1e-4, written (64MB)
//   k: hnK = 0.5|k_s|^2 written; blockmax(proj-hn) -> atomicMax kmax
// vs R8 maxes3: NO kh emission; omega LDS unpadded+swizzled (32KB); phi
// restage reuses omega buffer in two 128-col halves. LDS ~33KB -> 4 blk/CU.
// ============================================================================
__global__ __launch_bounds__(256, 2) void k_maxes4(
    const float* __restrict__ q, const float* __restrict__ kx,
    const float* __restrict__ omega, uint_t* __restrict__ kmax,
    half_t* __restrict__ phiQ, float* __restrict__ hnKg)
{
  __shared__ half_t Wl[256 * 64];   // omega swz; reused as phi staging [64][136]
  __shared__ float nrm[64];
  __shared__ float red[4];

  const int tid = threadIdx.x;
  const int lane = tid & 63;
  const int w = tid >> 6;
  const int lc = lane & 15, rg = lane >> 4, koff = rg * 8;
  const int swz = (lc & 7) << 3;
  const size_t rowbase = (size_t)blockIdx.x * 64;

  // omega fp32 -> f16 LDS, row-swizzled
  for (int l = tid; l < 2048; l += 256) {
    int m = l >> 3, d8 = (l & 7) * 8;
    float4 a = *(const float4*)(omega + m * 64 + d8);
    float4 b = *(const float4*)(omega + m * 64 + d8 + 4);
    *(half8*)&Wl[m * 64 + (d8 ^ ((m & 7) << 3))] = cvt_h8(a, b);
  }
  // q,k a-frags direct to regs; k row norms via shfl; write hnK
  half8 aq[2], akf[2];
  {
    const float* qp = q + (rowbase + w * 16 + lc) * 64 + koff;
    const float* kp = kx + (rowbase + w * 16 + lc) * 64 + koff;
    float pn = 0.f;
    #pragma unroll
    for (int ks = 0; ks < 2; ks++) {
      float4 a = *(const float4*)(qp + ks * 32);
      float4 b = *(const float4*)(qp + ks * 32 + 4);
      a.x *= SCALE; a.y *= SCALE; a.z *= SCALE; a.w *= SCALE;
      b.x *= SCALE; b.y *= SCALE; b.z *= SCALE; b.w *= SCALE;
      aq[ks] = cvt_h8(a, b);
      float4 c = *(const float4*)(kp + ks * 32);
      float4 d = *(const float4*)(kp + ks * 32 + 4);
      c.x *= SCALE; c.y *= SCALE; c.z *= SCALE; c.w *= SCALE;
      d.x *= SCALE; d.y *= SCALE; d.z *= SCALE; d.w *= SCALE;
      pn += c.x * c.x + c.y * c.y + c.z * c.z + c.w * c.w
          + d.x * d.x + d.y * d.y + d.z * d.z + d.w * d.w;
      akf[ks] = cvt_h8(c, d);
    }
    pn += __shfl_xor(pn, 16, 64);
    pn += __shfl_xor(pn, 32, 64);
    if (rg == 0) {
      nrm[w * 16 + lc] = 0.5f * pn;
      hnKg[rowbase + w * 16 + lc] = 0.5f * pn;
    }
  }
  __syncthreads();

  // ---- k proj -> block max ----
  {
    f32x4 acck[16];
    #pragma unroll
    for (int ct = 0; ct < 16; ct++) acck[ct] = (f32x4){0.f, 0.f, 0.f, 0.f};
    #pragma unroll
    for (int ks = 0; ks < 2; ks++)
      #pragma unroll
      for (int ct = 0; ct < 16; ct++) {
        half8 b = *(const half8*)&Wl[(ct * 16 + lc) * 64 + ((ks * 32 + koff) ^ swz)];
        acck[ct] = mfma16(akf[ks], b, acck[ct]);
      }
    float hn[4];
    #pragma unroll
    for (int r = 0; r < 4; r++) hn[r] = nrm[w * 16 + rg * 4 + r];
    float bm = -3.4e38f;
    #pragma unroll
    for (int ct = 0; ct < 16; ct++)
      #pragma unroll
      for (int r = 0; r < 4; r++) bm = fmaxf(bm, acck[ct][r] - hn[r]);
    #pragma unroll
    for (int off = 1; off < 64; off <<= 1) bm = fmaxf(bm, __shfl_xor(bm, off, 64));
    if (lane == 0) red[w] = bm;
  }

  // ---- q proj -> rowmax -> phi (in-place) ----
  f32x4 acc[16];
  #pragma unroll
  for (int ct = 0; ct < 16; ct++) acc[ct] = (f32x4){0.f, 0.f, 0.f, 0.f};
  #pragma unroll
  for (int ks = 0; ks < 2; ks++)
    #pragma unroll
    for (int ct = 0; ct < 16; ct++) {
      half8 b = *(const half8*)&Wl[(ct * 16 + lc) * 64 + ((ks * 32 + koff) ^ swz)];
      acc[ct] = mfma16(aq[ks], b, acc[ct]);
    }
  float rowm[4];
  #pragma unroll
  for (int r = 0; r < 4; r++) {
    float m0 = -3.4e38f;
    #pragma unroll
    for (int ct = 0; ct < 16; ct++) m0 = fmaxf(m0, acc[ct][r]);
    m0 = fmaxf(m0, __shfl_xor(m0, 1, 64));
    m0 = fmaxf(m0, __shfl_xor(m0, 2, 64));
    m0 = fmaxf(m0, __shfl_xor(m0, 4, 64));
    m0 = fmaxf(m0, __shfl_xor(m0, 8, 64));
    rowm[r] = m0;
  }
  #pragma unroll
  for (int ct = 0; ct < 16; ct++)
    #pragma unroll
    for (int r = 0; r < 4; r++)
      acc[ct][r] = __expf(acc[ct][r] - rowm[r]) * 0.0625f + 1e-4f;

  __syncthreads();   // all Wl reads done; red ready
  if (tid == 0)
    atomicMax(kmax, enc_f(fmaxf(fmaxf(red[0], red[1]), fmaxf(red[2], red[3]))));

  // ---- phi restage in two 128-col halves (reuses Wl: [64][136] = 17408 f16) ----
  half_t* st = Wl;
  #pragma unroll
  for (int hh = 0; hh < 2; hh++) {
    if (hh) __syncthreads();   // prev half's reads done
    #pragma unroll
    for (int c8 = 0; c8 < 8; c8++)
      #pragma unroll
      for (int r = 0; r < 4; r++)
        st[(w * 16 + rg * 4 + r) * 136 + c8 * 16 + lc] = (half_t)acc[hh * 8 + c8][r];
    __syncthreads();
    #pragma unroll
    for (int e = 0; e < 4; e++) {
      int l = tid + e * 256;           // 1024 half8 = 64 rows x 16 chunks
      int row = l >> 4, c = (l & 15) * 8;
      *(half8*)(phiQ + (rowbase + row) * 256 + hh * 128 + c) =
          *(const half8*)&st[row * 136 + c];
    }
  }
}

// ============================================================================
// k_state4: fused phi_k projection + chunk partial state + phiK emission.
// vs R8 state3: reads k fp32 directly (no kh); omega unpadded+swz (32KB);
// vt swz [80][128] (20.5KB); pkT/PhS alias omega as swz [128][128] (32KB).
// LDS 53.3KB -> 3 blocks/CU.
// ============================================================================
__global__ __launch_bounds__(256, 2) void k_state4(
    const float* __restrict__ kx, const float* __restrict__ v,
    const float* __restrict__ omega, const float* __restrict__ hnKg,
    const uint_t* __restrict__ kmax, half_t* __restrict__ spA,
    half_t* __restrict__ phiKg)
{
  __shared__ half_t WP[256 * 64];   // omega swz; aliased by pkT/PhS [128][128] swz
  __shared__ half_t vt[80 * 128];   // [d'][j] swz; row64=ones; 65..79 garbage(ok)

  const int tid = threadIdx.x;
  const int lane = tid & 63;
  const int w = tid >> 6;
  const int lc = lane & 15, rg = lane >> 4, koff = rg * 8;
  const int wr = w * 32;
  const int swz = (lc & 7) << 3;
  const int blk = blockIdx.x;
  const size_t nbase = (size_t)(blk >> 5) * NSEQ + (size_t)(blk & 31) * CHUNK;
  const float gmaxv = dec_f(*kmax);

  // omega fp32 -> f16 LDS, row-swizzled
  for (int l = tid; l < 2048; l += 256) {
    int m = l >> 3, d8 = (l & 7) * 8;
    float4 a = *(const float4*)(omega + m * 64 + d8);
    float4 b = *(const float4*)(omega + m * 64 + d8 + 4);
    *(half8*)&WP[m * 64 + (d8 ^ ((m & 7) << 3))] = cvt_h8(a, b);
  }
  // v^T -> f16 LDS (swizzled), ones row
  for (int l = tid; l < 2048; l += 256) {
    int j = l >> 4, dq = (l & 15) * 4;
    float4 vv = *(const float4*)(v + (nbase + j) * 64 + dq);
    vt[(dq + 0) * 128 + (j ^ (((dq + 0) & 7) << 3))] = (half_t)vv.x;
    vt[(dq + 1) * 128 + (j ^ (((dq + 1) & 7) << 3))] = (half_t)vv.y;
    vt[(dq + 2) * 128 + (j ^ (((dq + 2) & 7) << 3))] = (half_t)vv.z;
    vt[(dq + 3) * 128 + (j ^ (((dq + 3) & 7) << 3))] = (half_t)vv.w;
  }
  if (tid < 128) vt[64 * 128 + tid] = (half_t)1.0f;   // (64&7)=0: no swz

  // k a-frags from f32 (scale+cvt, identical values to old kh path) + hnK
  half8 ak[2][2];
  float hnr[2][4];
  #pragma unroll
  for (int rt = 0; rt < 2; rt++) {
    const float* kp = kx + (nbase + wr + rt * 16 + lc) * 64 + koff;
    #pragma unroll
    for (int ks = 0; ks < 2; ks++) {
      float4 a = *(const float4*)(kp + ks * 32);
      float4 b = *(const float4*)(kp + ks * 32 + 4);
      a.x *= SCALE; a.y *= SCALE; a.z *= SCALE; a.w *= SCALE;
      b.x *= SCALE; b.y *= SCALE; b.z *= SCALE; b.w *= SCALE;
      ak[rt][ks] = cvt_h8(a, b);
    }
    #pragma unroll
    for (int r = 0; r < 4; r++)
      hnr[rt][r] = hnKg[nbase + wr + rt * 16 + rg * 4 + r];
  }
  __syncthreads();

  // proj k over all 256 m (swizzled omega reads)
  f32x4 accP[2][16];
  #pragma unroll
  for (int rt = 0; rt < 2; rt++)
    #pragma unroll
    for (int ct = 0; ct < 16; ct++) accP[rt][ct] = (f32x4){0.f, 0.f, 0.f, 0.f};
  #pragma unroll
  for (int ks = 0; ks < 2; ks++)
    #pragma unroll
    for (int ct = 0; ct < 16; ct++) {
      half8 b = *(const half8*)&WP[(ct * 16 + lc) * 64 + ((ks * 32 + koff) ^ swz)];
      accP[0][ct] = mfma16(ak[0][ks], b, accP[0][ct]);
      accP[1][ct] = mfma16(ak[1][ks], b, accP[1][ct]);
    }
  #pragma unroll
  for (int rt = 0; rt < 2; rt++)
    #pragma unroll
    for (int ct = 0; ct < 16; ct++)
      #pragma unroll
      for (int r = 0; r < 4; r++)
        accP[rt][ct][r] = __expf(accP[rt][ct][r] - hnr[rt][r] - gmaxv) * 0.0625f + 1e-4f;

  // two m-halves: transpose phiK into pkT (alias WP, swz), then state MFMA
  half_t* pkT = WP;  // [128][128] swz: col j at row m swizzled by (m&7)<<3
  #pragma unroll
  for (int h = 0; h < 2; h++) {
    __syncthreads();   // h=0: proj reads of WP done; h=1: prev MFMA reads done
    #pragma unroll
    for (int rt = 0; rt < 2; rt++)
      #pragma unroll
      for (int c8 = 0; c8 < 8; c8++) {
        int m = c8 * 16 + lc;
        int ct = h * 8 + c8;
        #pragma unroll
        for (int r = 0; r < 4; r++) {
          int j = wr + rt * 16 + rg * 4 + r;
          pkT[m * 128 + (j ^ ((m & 7) << 3))] = (half_t)accP[rt][ct][r];
        }
      }
    __syncthreads();
    f32x4 acc2[5][2];
    #pragma unroll
    for (int rt = 0; rt < 5; rt++) {
      acc2[rt][0] = (f32x4){0.f, 0.f, 0.f, 0.f};
      acc2[rt][1] = (f32x4){0.f, 0.f, 0.f, 0.f};
    }
    #pragma unroll
    for (int ks = 0; ks < 4; ks++) {
      half8 b0 = *(const half8*)&pkT[((2 * w + 0) * 16 + lc) * 128 + ((ks * 32 + koff) ^ swz)];
      half8 b1 = *(const half8*)&pkT[((2 * w + 1) * 16 + lc) * 128 + ((ks * 32 + koff) ^ swz)];
      #pragma unroll
      for (int rt = 0; rt < 5; rt++) {
        half8 a = *(const half8*)&vt[(rt * 16 + lc) * 128 + ((ks * 32 + koff) ^ swz)];
        acc2[rt][0] = mfma16(a, b0, acc2[rt][0]);
        acc2[rt][1] = mfma16(a, b1, acc2[rt][1]);
      }
    }
    #pragma unroll
    for (int rt = 0; rt < 5; rt++)
      #pragma unroll
      for (int c2 = 0; c2 < 2; c2++)
        #pragma unroll
        for (int r = 0; r < 4; r++) {
          int row = rt * 16 + rg * 4 + r;
          if (row < SROW)
            spA[(size_t)blk * SPITCH + row * 256 + h * 128 + (2 * w + c2) * 16 + lc] =
                (half_t)acc2[rt][c2][r];
        }
  }

  // ---- phiK emission: restage accP -> PhS[j][m-half] swz, coalesced write ----
  half_t* PhS = WP;  // [128][128] swz by (j&7)<<3 on the m axis
  #pragma unroll
  for (int hh = 0; hh < 2; hh++) {
    __syncthreads();   // prev reads of alias complete
    #pragma unroll
    for (int rt = 0; rt < 2; rt++)
      #pragma unroll
      for (int c8 = 0; c8 < 8; c8++)
        #pragma unroll
        for (int r = 0; r < 4; r++) {
          int j = wr + rt * 16 + rg * 4 + r;
          PhS[j * 128 + ((c8 * 16 + lc) ^ ((j & 7) << 3))] =
              (half_t)accP[rt][hh * 8 + c8][r];
        }
    __syncthreads();
    #pragma unroll
    for (int e = 0; e < 8; e++) {
      int l = tid + e * 256;           // 2048 half8 = 128 rows x 16 chunks
      int j = l >> 4, c8b = (l & 15) * 8;
      *(half8*)(phiKg + (nbase + j) * 256 + hh * 128 + c8b) =
          *(const half8*)&PhS[j * 128 + (c8b ^ ((j & 7) << 3))];
    }
  }
}

// ============================================================================
// k_prefix: exclusive prefix over 32 chunks, f16->f16, fp32 accum (unchanged).
// ============================================================================
__global__ __launch_bounds__(256) void k_prefix(
    const uint_t* __restrict__ spA, uint_t* __restrict__ spB)
{
  int r = blockIdx.x * 256 + threadIdx.x;
  if (r >= SPITCH / 2) return;
  int bh = blockIdx.y;
  const uint_t* src = spA + (size_t)bh * NCH * (SPITCH / 2) + r;
  uint_t* dst = spB + (size_t)bh * NCH * (SPITCH / 2) + r;
  float r0 = 0.f, r1 = 0.f;
  for (int c = 0; c < NCH; c++) {
    union { uint_t u; half_t h[2]; } cv, ov;
    cv.u = src[(size_t)c * (SPITCH / 2)];
    ov.h[0] = (half_t)r0; ov.h[1] = (half_t)r1;
    dst[(size_t)c * (SPITCH / 2)] = ov.u;
    r0 += (float)cv.h[0];
    r1 += (float)cv.h[1];
  }
}

// ============================================================================
// k_attn8: pure consumer, transposed formulation, 512 threads (UNCHANGED R8).
// ============================================================================
__global__ __launch_bounds__(512) void k_attn8(
    const half_t* __restrict__ phiQ, const half_t* __restrict__ phiK,
    const float* __restrict__ v, const half_t* __restrict__ spB,
    float* __restrict__ out)
{
  __shared__ half_t sm[18432];
  half_t* PQ  = sm;            // [128][64] swz
  half_t* SST = sm + 8192;     // [80][64] swz (rows 0..64 valid)
  half_t* AS  = sm;            // phase2 alias
  half_t* VT  = sm + 8192;     // phase2 [80][128] swz

  const int tid = threadIdx.x;
  const int lane = tid & 63;
  const int w = tid >> 6;                 // 0..7
  const int lc = lane & 15, rg = lane >> 4, koff = rg * 8;
  const int blk = blockIdx.x;
  const size_t nbase = (size_t)(blk >> 5) * NSEQ + (size_t)(blk & 31) * CHUNK;
  const half_t* spb = spB + (size_t)blk * SPITCH;
  const int swz = (lc & 7) << 3;

  f32x4 accA[8], accO[5];
  #pragma unroll
  for (int it = 0; it < 8; it++) accA[it] = (f32x4){0.f, 0.f, 0.f, 0.f};
  #pragma unroll
  for (int cs = 0; cs < 5; cs++) accO[cs] = (f32x4){0.f, 0.f, 0.f, 0.f};

  // ---- phase 1: 4 m-tiles ----
  for (int mt = 0; mt < 4; mt++) {
    if (mt) __syncthreads();
    #pragma unroll
    for (int e = 0; e < 2; e++) {
      int l = tid + e * 512;
      int ro = l >> 3, c8 = (l & 7) * 8;
      *(half8*)&PQ[ro * 64 + (c8 ^ ((ro & 7) << 3))] =
          *(const half8*)(phiQ + (nbase + ro) * 256 + mt * 64 + c8);
    }
    { int ro = tid >> 3, c8 = (tid & 7) * 8;
      if (tid < 520)
        *(half8*)&SST[ro * 64 + (c8 ^ ((ro & 7) << 3))] =
            *(const half8*)(spb + ro * 256 + mt * 64 + c8); }
    if (tid < 8) { int l = tid + 512; int ro = l >> 3, c8 = (l & 7) * 8;
      *(half8*)&SST[ro * 64 + (c8 ^ ((ro & 7) << 3))] =
          *(const half8*)(spb + ro * 256 + mt * 64 + c8); }
    half8 af0 = *(const half8*)(phiK + (nbase + w * 16 + lc) * 256 + mt * 64 + koff);
    half8 af1 = *(const half8*)(phiK + (nbase + w * 16 + lc) * 256 + mt * 64 + 32 + koff);
    __syncthreads();
    #pragma unroll
    for (int ks2 = 0; ks2 < 64; ks2 += 32) {
      half8 a = ks2 ? af1 : af0;
      int sA = (ks2 + koff) ^ swz;
      half8 bO = *(const half8*)&PQ[(w * 16 + lc) * 64 + sA];
      #pragma unroll
      for (int it = 0; it < 8; it++) {
        half8 b = *(const half8*)&PQ[(it * 16 + lc) * 64 + sA];
        accA[it] = mfma16(a, b, accA[it]);
      }
      #pragma unroll
      for (int cs = 0; cs < 5; cs++) {
        half8 as_ = *(const half8*)&SST[(cs * 16 + lc) * 64 + sA];
        accO[cs] = mfma16(as_, bO, accO[cs]);
      }
    }
  }
  __syncthreads();

  // ---- phase 2: VT stage + masked A @ v in two j-halves ----
  #pragma unroll
  for (int e = 0; e < 4; e++) {
    int l = tid + e * 512;
    int j = l >> 4, dq = (l & 15) * 4;
    float4 vv = *(const float4*)(v + (nbase + j) * 64 + dq);
    VT[(dq + 0) * 128 + (j ^ (((dq + 0) & 7) << 3))] = (half_t)vv.x;
    VT[(dq + 1) * 128 + (j ^ (((dq + 1) & 7) << 3))] = (half_t)vv.y;
    VT[(dq + 2) * 128 + (j ^ (((dq + 2) & 7) << 3))] = (half_t)vv.z;
    VT[(dq + 3) * 128 + (j ^ (((dq + 3) & 7) << 3))] = (half_t)vv.w;
  }
  if (tid < 128) VT[64 * 128 + tid] = (half_t)1.0f;

  #pragma unroll
  for (int h = 0; h < 2; h++) {
    if ((w >> 2) == h) {
      #pragma unroll
      for (int it = 0; it < 8; it++) {
        int i = it * 16 + lc;
        #pragma unroll
        for (int r = 0; r < 4; r++) {
          int j = w * 16 + rg * 4 + r;
          float val = (j <= i) ? accA[it][r] : 0.f;
          AS[i * 64 + ((j - h * 64) ^ ((i & 7) << 3))] = (half_t)val;
        }
      }
    }
    __syncthreads();
    #pragma unroll
    for (int ks2 = 0; ks2 < 64; ks2 += 32) {
      int sj = (ks2 + koff) ^ swz;
      half8 b = *(const half8*)&AS[(w * 16 + lc) * 64 + sj];
      #pragma unroll
      for (int cs = 0; cs < 5; cs++) {
        half8 a = *(const half8*)&VT[(cs * 16 + lc) * 128 + ((h * 64 + ks2 + koff) ^ swz)];
        accO[cs] = mfma16(a, b, accO[cs]);
      }
    }
    __syncthreads();
  }

  // ---- epilogue ----
  float den = __shfl(accO[4][0], lane & 15, 64) + 1e-6f;
  float inv = 1.0f / den;
  float* OS = (float*)sm;   // [128][68]
  #pragma unroll
  for (int cs = 0; cs < 4; cs++)
    #pragma unroll
    for (int r = 0; r < 4; r++)
      OS[(w * 16 + lc) * 68 + cs * 16 + rg * 4 + r] = accO[cs][r] * inv;
  __syncthreads();
  #pragma unroll
  for (int e = 0; e < 4; e++) {
    int l = tid + e * 512;
    int row = l >> 4, c4 = (l & 15) * 4;
    *(float4*)(out + (nbase + row) * 64 + c4) = *(const float4*)&OS[row * 68 + c4];
  }
}

// ============================================================================
// launcher
// ws layout:
//   hnK  f32 @0          (512K)
//   spB  f16 @524288     (34,078,720)
//   phiQ f16 @34603008   (64M)
//   phiK f16 @101711872  (64M)
//   spA  f16 @168820736  (34,078,720)
//   kmax u32 @202899456            -> ~202.9 MB total
// ============================================================================
extern "C" void kernel_launch(void* const* d_in, const int* in_sizes, int n_in,
                              void* d_out, int out_size, void* d_ws, size_t ws_size,
                              hipStream_t stream) {
  const float* q = (const float*)d_in[0];
  const float* k = (const float*)d_in[1];
  const float* v = (const float*)d_in[2];
  const float* omega = (const float*)d_in[3];
  float* out = (float*)d_out;
  char* ws = (char*)d_ws;

  float*  hnKg = (float*)(ws + 0);
  half_t* spB  = (half_t*)(ws + 524288);
  half_t* phiQ = (half_t*)(ws + 34603008);
  half_t* phiK = (half_t*)(ws + 101711872);
  half_t* spA  = (half_t*)(ws + 168820736);
  uint_t* kmax = (uint_t*)(ws + 202899456);

  k_init<<<1, 1, 0, stream>>>(kmax);
  k_maxes4<<<2048, 256, 0, stream>>>(q, k, omega, kmax, phiQ, hnKg);
  k_state4<<<1024, 256, 0, stream>>>(k, v, omega, hnKg, kmax, spA, phiK);
  k_prefix<<<dim3(33, 32), 256, 0, stream>>>((const uint_t*)spA, (uint_t*)spB);
  k_attn8<<<1024, 512, 0, stream>>>(phiQ, phiK, v, spB, out);
}